// Round 4
// baseline (335.591 us; speedup 1.0000x reference)
//
#include <hip/hip_runtime.h>
#include <hip/hip_bf16.h>

#define EDIM     512
#define NTOK     (512 * 128) // B*S = 65536
#define NTHREADS 256

typedef unsigned short u16;
typedef unsigned int   u32;

__device__ __forceinline__ float bf2f(u16 u) { return __uint_as_float(((u32)u) << 16); }

__device__ __forceinline__ u32 f2bfbits(float f) {
    // round-to-nearest-even f32 -> bf16
    u32 b = __float_as_uint(f);
    return (b + 0x7fffu + ((b >> 16) & 1u)) >> 16;
}

// ---- 3-way container detection ---------------------------------------------
// Inspect first 512 u32 words of x:
//   true bf16 container : low u16 of each word is a valid N(0,1)-scale bf16
//                         (nonzero exponent in [96,143]) -> v ~ 512, z ~ 0
//   true f32 container  : low u16 = random mantissa bits -> v ~ 19%, z ~ 0
//   f32 container holding bf16-ROUNDED values: low u16 == 0 -> z ~ 512
// flag = 1 only for a true bf16 container; else 0 (f32 layout).
__global__ void detect_dtype(const u32* __restrict__ x, int* __restrict__ flag)
{
    __shared__ int zc, vc;
    if (threadIdx.x == 0) { zc = 0; vc = 0; }
    __syncthreads();
    int z = 0, v = 0;
    #pragma unroll
    for (int i = 0; i < 2; ++i) {
        const u32 w = x[threadIdx.x + 256 * i];
        if ((w & 0xFFFFu) == 0u) z++;
        const u32 e = (w >> 7) & 0xFFu;
        if (e != 0u && e >= 96u && e <= 143u) v++;
    }
    atomicAdd(&zc, z);
    atomicAdd(&vc, v);
    __syncthreads();
    if (threadIdx.x == 0) *flag = (zc < 384 && vc >= 384) ? 1 : 0;
}

// ---- dtype-generic scalar load ---------------------------------------------
template<bool BF16>
__device__ __forceinline__ float ld1(const void* p, size_t off) {
    if constexpr (BF16) return bf2f(((const u16*)p)[off]);
    else                return ((const float*)p)[off];
}

// ---- literal per-token pipeline --------------------------------------------
template<bool BF16>
__device__ __forceinline__ void body(
    const void* __restrict__ x,
    const void* __restrict__ qwp,  // [2][8]
    const void* __restrict__ Wq,   // [4][512]
    const void* __restrict__ bq,   // [4]
    const void* __restrict__ Wc,   // [512][4]
    const void* __restrict__ bc,   // [512]
    void* __restrict__ out,
    float (*s_wq)[EDIM],           // [4][512]
    float (*s_wc)[4],              // [512][4]
    float* s_bc)                   // [512]
{
    const int tid = threadIdx.x;

    // cooperative LDS staging of the (tiny) weights
    for (int i = tid; i < 4 * EDIM; i += NTHREADS) s_wq[i >> 9][i & 511] = ld1<BF16>(Wq, i);
    for (int i = tid; i < 4 * EDIM; i += NTHREADS) s_wc[i >> 2][i & 3]   = ld1<BF16>(Wc, i);
    for (int i = tid; i < EDIM;     i += NTHREADS) s_bc[i]               = ld1<BF16>(bc, i);
    __syncthreads();

    float qwv[16];
    #pragma unroll
    for (int i = 0; i < 16; ++i) qwv[i] = ld1<BF16>(qwp, i);

    const int n = blockIdx.x * NTHREADS + tid;
    if (n >= NTOK) return;

    // ---- stage 1: q_in = x[n,:] @ Wq^T + bq ----
    float acc[4];
    #pragma unroll
    for (int q = 0; q < 4; ++q) acc[q] = ld1<BF16>(bq, q);
    for (int e = 0; e < EDIM; ++e) {
        const float xe = ld1<BF16>(x, (size_t)n * EDIM + e);
        #pragma unroll
        for (int q = 0; q < 4; ++q) acc[q] = fmaf(xe, s_wq[q][e], acc[q]);
    }

    // ---- stage 2: literal 4-qubit circuit ----
    // AngleEmbedding RX product state, wire 0 = MSB; amp = [cos, -i sin]
    float cw[4], sw[4];
    #pragma unroll
    for (int w = 0; w < 4; ++w) {
        cw[w] = cosf(0.5f * acc[w]);
        sw[w] = sinf(0.5f * acc[w]);
    }
    float re[16], im[16];
    re[0] = 1.f; im[0] = 0.f;
    #pragma unroll
    for (int w = 0; w < 4; ++w) {
        #pragma unroll
        for (int j = (1 << w) - 1; j >= 0; --j) {
            const float r0 = re[j], i0 = im[j];
            re[2 * j]     = r0 * cw[w];
            im[2 * j]     = i0 * cw[w];
            re[2 * j + 1] = i0 * sw[w];
            im[2 * j + 1] = -r0 * sw[w];
        }
    }
    #pragma unroll
    for (int l = 0; l < 2; ++l) {
        // ring of CRZ(phi, wires=[i, (i+1)%4]) — diagonal
        #pragma unroll
        for (int i = 0; i < 4; ++i) {
            const float phi = qwv[l * 8 + i];
            const float cc = cosf(0.5f * phi);
            const float ss = sinf(0.5f * phi);
            #pragma unroll
            for (int k = 0; k < 16; ++k) {
                const int cb = (k >> (3 - i)) & 1;
                const int tb = (k >> (3 - ((i + 1) & 3))) & 1;
                if (cb) {
                    const float pr = cc, pi = tb ? ss : -ss;  // e^{i*0.5*phi*(2tb-1)}
                    const float r = re[k], m = im[k];
                    re[k] = r * pr - m * pi;
                    im[k] = r * pi + m * pr;
                }
            }
        }
        // RY(theta) on each wire i: bit (3-i), stride 8>>i
        #pragma unroll
        for (int i = 0; i < 4; ++i) {
            const float th = 0.5f * qwv[l * 8 + 4 + i];
            const float ct = cosf(th), st = sinf(th);
            const int str = 8 >> i;
            #pragma unroll
            for (int k = 0; k < 16; ++k) {
                if ((k & str) == 0) {
                    const int k1 = k + str;
                    const float r0 = re[k], r1 = re[k1];
                    const float i0 = im[k], i1 = im[k1];
                    re[k]  = ct * r0 - st * r1;
                    re[k1] = st * r0 + ct * r1;
                    im[k]  = ct * i0 - st * i1;
                    im[k1] = st * i0 + ct * i1;
                }
            }
        }
    }
    float qout[4] = {0.f, 0.f, 0.f, 0.f};
    #pragma unroll
    for (int k = 0; k < 16; ++k) {
        const float p = re[k] * re[k] + im[k] * im[k];
        #pragma unroll
        for (int q = 0; q < 4; ++q)
            qout[q] += ((k >> (3 - q)) & 1) ? -p : p;
    }

    // ---- stage 3: out[n,:] = q_out @ Wc^T + bc ----
    for (int e = 0; e < EDIM; ++e) {
        float o = s_bc[e];
        #pragma unroll
        for (int q = 0; q < 4; ++q) o = fmaf(qout[q], s_wc[e][q], o);
        if constexpr (BF16) ((u16*)out)[(size_t)n * EDIM + e] = (u16)f2bfbits(o);
        else                ((float*)out)[(size_t)n * EDIM + e] = o;
    }
}

__global__ __launch_bounds__(NTHREADS)
void qlayer_kernel(const void* __restrict__ x,
                   const void* __restrict__ qw,
                   const void* __restrict__ Wq,
                   const void* __restrict__ bq,
                   const void* __restrict__ Wc,
                   const void* __restrict__ bc,
                   void* __restrict__ out,
                   const int* __restrict__ flag)
{
    __shared__ float s_wq[4][EDIM];
    __shared__ float s_wc[EDIM][4];
    __shared__ float s_bc[EDIM];

    const bool isbf = flag ? (*flag == 1) : false;  // uniform branch
    if (isbf)
        body<true >(x, qw, Wq, bq, Wc, bc, out, s_wq, s_wc, s_bc);
    else
        body<false>(x, qw, Wq, bq, Wc, bc, out, s_wq, s_wc, s_bc);
}

extern "C" void kernel_launch(void* const* d_in, const int* in_sizes, int n_in,
                              void* d_out, int out_size, void* d_ws, size_t ws_size,
                              hipStream_t stream)
{
    const void* x  = d_in[0];
    const void* qw = d_in[1];
    const void* Wq = d_in[2];
    const void* bq = d_in[3];
    const void* Wc = d_in[4];
    const void* bc = d_in[5];
    (void)in_sizes; (void)n_in; (void)out_size;

    int* flag = nullptr;
    if (ws_size >= sizeof(int)) {
        flag = (int*)d_ws;
        detect_dtype<<<1, 256, 0, stream>>>((const u32*)x, flag);
    }
    const int blocks = NTOK / NTHREADS; // 256 blocks x 256 threads, 1 token/thread
    qlayer_kernel<<<blocks, NTHREADS, 0, stream>>>(x, qw, Wq, bq, Wc, bc, d_out, flag);
}